// Round 1
// baseline (1379.098 us; speedup 1.0000x reference)
//
#include <hip/hip_runtime.h>

#define NF0 300
#define F1 128
#define F2 64

// ---------------- CSR build ----------------

__global__ void hist_k(const int* __restrict__ dst, int* __restrict__ cnt, int E) {
    int i = blockIdx.x * blockDim.x + threadIdx.x;
    int stride = gridDim.x * blockDim.x;
    for (; i < E; i += stride) atomicAdd(&cnt[dst[i]], 1);
}

__global__ __launch_bounds__(1024) void scanA_k(const int* __restrict__ cnt, int* __restrict__ offs,
                                                int* __restrict__ partials, int n) {
    __shared__ int s[1024];
    int i = blockIdx.x * 1024 + threadIdx.x;
    int v = (i < n) ? cnt[i] : 0;
    s[threadIdx.x] = v;
    __syncthreads();
    for (int d = 1; d < 1024; d <<= 1) {
        int t = (threadIdx.x >= (unsigned)d) ? s[threadIdx.x - d] : 0;
        __syncthreads();
        s[threadIdx.x] += t;
        __syncthreads();
    }
    if (i < n) offs[i] = s[threadIdx.x] - v;  // exclusive within chunk
    if (threadIdx.x == 1023) partials[blockIdx.x] = s[1023];
}

__global__ __launch_bounds__(128) void scanB_k(int* __restrict__ partials, int nchunks) {
    __shared__ int s[128];
    int v = (threadIdx.x < nchunks) ? partials[threadIdx.x] : 0;
    s[threadIdx.x] = v;
    __syncthreads();
    for (int d = 1; d < 128; d <<= 1) {
        int t = (threadIdx.x >= (unsigned)d) ? s[threadIdx.x - d] : 0;
        __syncthreads();
        s[threadIdx.x] += t;
        __syncthreads();
    }
    if (threadIdx.x < nchunks) partials[threadIdx.x] = s[threadIdx.x] - v;  // exclusive
}

__global__ void scanC_k(int* __restrict__ offs, const int* __restrict__ partials, int* __restrict__ cursor,
                        const int* __restrict__ cnt, float* __restrict__ dinv, int n, int E) {
    int i = blockIdx.x * blockDim.x + threadIdx.x;
    if (i < n) {
        int o = offs[i] + partials[i >> 10];
        offs[i] = o;
        cursor[i] = o;
        dinv[i] = rsqrtf((float)cnt[i] + 1.0f);  // +1 for self-loop; deg>=1 always
    }
    if (i == 0) offs[n] = E;
}

__global__ void fill_k(const int* __restrict__ src, const int* __restrict__ dst, int* __restrict__ cursor,
                       int* __restrict__ slots, int E) {
    int i = blockIdx.x * blockDim.x + threadIdx.x;
    int stride = gridDim.x * blockDim.x;
    for (; i < E; i += stride) {
        int d = dst[i];
        int p = atomicAdd(&cursor[d], 1);
        slots[p] = src[i];
    }
}

// ---------------- GEMMs (fp32 vector; W fully in LDS; wave-per-row) ----------------

// y1[row][c] = dinv[row] * sum_k x[row][k]*W1[k][c]   (c = lane and lane+64)
__global__ __launch_bounds__(1024) void gemm1_k(const float* __restrict__ x, const float* __restrict__ W1,
                                                const float* __restrict__ dinv, float* __restrict__ y1, int n) {
    __shared__ float Ws[NF0 * F1];  // 153.6 KB
    {
        const float4* W4 = (const float4*)W1;
        float4* S4 = (float4*)Ws;
        for (int i = threadIdx.x; i < NF0 * F1 / 4; i += 1024) S4[i] = W4[i];
    }
    __syncthreads();
    int gtid = blockIdx.x * 1024 + threadIdx.x;
    int wid = gtid >> 6;
    int lane = threadIdx.x & 63;
    int nw = (gridDim.x * 1024) >> 6;
    for (int i = wid; i < n; i += nw) {
        int row = __builtin_amdgcn_readfirstlane(i);
        const float* xr = x + (size_t)row * NF0;
        float a0 = 0.f, a1 = 0.f;
#pragma unroll 4
        for (int k = 0; k < NF0; ++k) {
            float xv = xr[k];                       // wave-uniform -> scalar load
            a0 = fmaf(xv, Ws[k * F1 + lane], a0);   // 2-way bank alias = free
            a1 = fmaf(xv, Ws[k * F1 + 64 + lane], a1);
        }
        float dv = dinv[row];
        float* yr = y1 + (size_t)row * F1;
        yr[lane] = a0 * dv;
        yr[64 + lane] = a1 * dv;
    }
}

// y2[row][c] = dinv[row] * sum_k h[row][k]*W2[k][c]   (c = lane)
__global__ __launch_bounds__(256) void gemm2_k(const float* __restrict__ h, const float* __restrict__ W2,
                                               const float* __restrict__ dinv, float* __restrict__ y2, int n) {
    __shared__ float Ws[F1 * F2];  // 32 KB
    {
        const float4* W4 = (const float4*)W2;
        float4* S4 = (float4*)Ws;
        for (int i = threadIdx.x; i < F1 * F2 / 4; i += 256) S4[i] = W4[i];
    }
    __syncthreads();
    int gtid = blockIdx.x * 256 + threadIdx.x;
    int wid = gtid >> 6;
    int lane = threadIdx.x & 63;
    int nw = (gridDim.x * 256) >> 6;
    for (int i = wid; i < n; i += nw) {
        int row = __builtin_amdgcn_readfirstlane(i);
        const float* hr = h + (size_t)row * F1;
        float a = 0.f;
#pragma unroll 4
        for (int k = 0; k < F1; ++k) a = fmaf(hr[k], Ws[k * F2 + lane], a);
        y2[(size_t)row * F2 + lane] = a * dinv[row];
    }
}

// ---------------- Pull aggregation (CSR; wave-per-node; no float atomics) ----------------

// h[i][:] = relu(dinv[i]*(y1[i][:] + sum_{src in N(i)} y1[src][:]) + b1)
__global__ __launch_bounds__(256) void agg1_k(const float* __restrict__ y1, const int* __restrict__ offs,
                                              const int* __restrict__ slots, const float* __restrict__ dinv,
                                              const float* __restrict__ b1, float* __restrict__ hrelu, int n) {
    int gtid = blockIdx.x * 256 + threadIdx.x;
    int wid = gtid >> 6, lane = threadIdx.x & 63;
    int nw = (gridDim.x * 256) >> 6;
    int c = lane * 2;
    for (int i = wid; i < n; i += nw) {
        int row = __builtin_amdgcn_readfirstlane(i);
        int beg = offs[row], end = offs[row + 1];
        float2 acc = *(const float2*)(y1 + (size_t)row * F1 + c);  // self-loop term
        int j = beg;
        while (j < end) {
            int m = min(64, end - j);
            int sv = (lane < m) ? slots[j + lane] : 0;
            int t = 0;
            for (; t + 4 <= m; t += 4) {  // 4 loads in flight
                int s0 = __shfl(sv, t), s1 = __shfl(sv, t + 1), s2 = __shfl(sv, t + 2), s3 = __shfl(sv, t + 3);
                float2 v0 = *(const float2*)(y1 + (size_t)s0 * F1 + c);
                float2 v1 = *(const float2*)(y1 + (size_t)s1 * F1 + c);
                float2 v2 = *(const float2*)(y1 + (size_t)s2 * F1 + c);
                float2 v3 = *(const float2*)(y1 + (size_t)s3 * F1 + c);
                acc.x += v0.x + v1.x + v2.x + v3.x;
                acc.y += v0.y + v1.y + v2.y + v3.y;
            }
            for (; t < m; ++t) {
                int s = __shfl(sv, t);
                float2 v = *(const float2*)(y1 + (size_t)s * F1 + c);
                acc.x += v.x;
                acc.y += v.y;
            }
            j += m;
        }
        float dv = dinv[row];
        float2 bb = *(const float2*)(b1 + c);
        float2 hv;
        hv.x = fmaxf(fmaf(acc.x, dv, bb.x), 0.f);
        hv.y = fmaxf(fmaf(acc.y, dv, bb.y), 0.f);
        *(float2*)(hrelu + (size_t)row * F1 + c) = hv;
    }
}

// out[i][:] = dinv[i]*(y2[i][:] + sum_{src in N(i)} y2[src][:]) + b2
__global__ __launch_bounds__(256) void agg2_k(const float* __restrict__ y2, const int* __restrict__ offs,
                                              const int* __restrict__ slots, const float* __restrict__ dinv,
                                              const float* __restrict__ b2, float* __restrict__ out, int n) {
    int gtid = blockIdx.x * 256 + threadIdx.x;
    int wid = gtid >> 6, lane = threadIdx.x & 63;
    int nw = (gridDim.x * 256) >> 6;
    for (int i = wid; i < n; i += nw) {
        int row = __builtin_amdgcn_readfirstlane(i);
        int beg = offs[row], end = offs[row + 1];
        float acc = y2[(size_t)row * F2 + lane];  // self-loop term
        int j = beg;
        while (j < end) {
            int m = min(64, end - j);
            int sv = (lane < m) ? slots[j + lane] : 0;
            int t = 0;
            for (; t + 4 <= m; t += 4) {
                int s0 = __shfl(sv, t), s1 = __shfl(sv, t + 1), s2 = __shfl(sv, t + 2), s3 = __shfl(sv, t + 3);
                float v0 = y2[(size_t)s0 * F2 + lane];
                float v1 = y2[(size_t)s1 * F2 + lane];
                float v2 = y2[(size_t)s2 * F2 + lane];
                float v3 = y2[(size_t)s3 * F2 + lane];
                acc += v0 + v1 + v2 + v3;
            }
            for (; t < m; ++t) {
                int s = __shfl(sv, t);
                acc += y2[(size_t)s * F2 + lane];
            }
            j += m;
        }
        out[(size_t)row * F2 + lane] = fmaf(acc, dinv[row], b2[lane]);
    }
}

// ---------------- launch ----------------

extern "C" void kernel_launch(void* const* d_in, const int* in_sizes, int n_in,
                              void* d_out, int out_size, void* d_ws, size_t ws_size,
                              hipStream_t stream) {
    const float* x  = (const float*)d_in[0];
    const int*   ei = (const int*)d_in[1];
    const float* W1 = (const float*)d_in[2];
    const float* b1 = (const float*)d_in[3];
    const float* W2 = (const float*)d_in[4];
    const float* b2 = (const float*)d_in[5];
    float* out = (float*)d_out;

    int n = in_sizes[0] / NF0;
    int E = in_sizes[1] / 2;
    const int* srcv = ei;      // edge_index[0]
    const int* dstv = ei + E;  // edge_index[1]

    char* ws = (char*)d_ws;
    size_t off = 0;
    auto alloc = [&](size_t bytes) -> void* {
        void* p = ws + off;
        off = (off + bytes + 255) & ~(size_t)255;
        return p;
    };
    float* dinv   = (float*)alloc((size_t)n * 4);
    int* cnt      = (int*)alloc((size_t)n * 4);
    int* offs     = (int*)alloc((size_t)(n + 1) * 4);
    int* cursor   = (int*)alloc((size_t)n * 4);
    int* partials = (int*)alloc(((size_t)(n + 1023) / 1024) * 4);
    int* slots    = (int*)alloc((size_t)E * 4);
    float* y1     = (float*)alloc((size_t)n * F1 * 4);
    float* hrelu  = (float*)alloc((size_t)n * F1 * 4);
    float* y2     = y1;  // y1 dead after agg1; reuse for layer-2 product

    int nchunks = (n + 1023) / 1024;

    hipMemsetAsync(cnt, 0, (size_t)n * 4, stream);
    hist_k<<<4096, 256, 0, stream>>>(dstv, cnt, E);
    scanA_k<<<nchunks, 1024, 0, stream>>>(cnt, offs, partials, n);
    scanB_k<<<1, 128, 0, stream>>>(partials, nchunks);
    scanC_k<<<(n + 255) / 256, 256, 0, stream>>>(offs, partials, cursor, cnt, dinv, n, E);
    fill_k<<<4096, 256, 0, stream>>>(srcv, dstv, cursor, slots, E);

    gemm1_k<<<256, 1024, 0, stream>>>(x, W1, dinv, y1, n);
    agg1_k<<<2048, 256, 0, stream>>>(y1, offs, slots, dinv, b1, hrelu, n);
    gemm2_k<<<1024, 256, 0, stream>>>(hrelu, W2, dinv, y2, n);
    agg2_k<<<2048, 256, 0, stream>>>(y2, offs, slots, dinv, b2, out, n);
}

// Round 2
// 1238.206 us; speedup vs baseline: 1.1138x; 1.1138x over previous
//
#include <hip/hip_runtime.h>

#define NF0 300
#define F1 128
#define F2 64

// ---------------- CSR build ----------------

__global__ void hist_k(const int* __restrict__ dst, int* __restrict__ cnt, int E) {
    int i = blockIdx.x * blockDim.x + threadIdx.x;
    int stride = gridDim.x * blockDim.x;
    for (; i < E; i += stride) atomicAdd(&cnt[dst[i]], 1);
}

__global__ __launch_bounds__(1024) void scanA_k(const int* __restrict__ cnt, int* __restrict__ offs,
                                                int* __restrict__ partials, int n) {
    __shared__ int s[1024];
    int i = blockIdx.x * 1024 + threadIdx.x;
    int v = (i < n) ? cnt[i] : 0;
    s[threadIdx.x] = v;
    __syncthreads();
    for (int d = 1; d < 1024; d <<= 1) {
        int t = (threadIdx.x >= (unsigned)d) ? s[threadIdx.x - d] : 0;
        __syncthreads();
        s[threadIdx.x] += t;
        __syncthreads();
    }
    if (i < n) offs[i] = s[threadIdx.x] - v;  // exclusive within chunk
    if (threadIdx.x == 1023) partials[blockIdx.x] = s[1023];
}

__global__ __launch_bounds__(128) void scanB_k(int* __restrict__ partials, int nchunks) {
    __shared__ int s[128];
    int v = (threadIdx.x < nchunks) ? partials[threadIdx.x] : 0;
    s[threadIdx.x] = v;
    __syncthreads();
    for (int d = 1; d < 128; d <<= 1) {
        int t = (threadIdx.x >= (unsigned)d) ? s[threadIdx.x - d] : 0;
        __syncthreads();
        s[threadIdx.x] += t;
        __syncthreads();
    }
    if (threadIdx.x < nchunks) partials[threadIdx.x] = s[threadIdx.x] - v;  // exclusive
}

__global__ void scanC_k(int* __restrict__ offs, const int* __restrict__ partials, int* __restrict__ cursor,
                        const int* __restrict__ cnt, float* __restrict__ dinv, int n, int E) {
    int i = blockIdx.x * blockDim.x + threadIdx.x;
    if (i < n) {
        int o = offs[i] + partials[i >> 10];
        offs[i] = o;
        cursor[i] = o;
        dinv[i] = rsqrtf((float)cnt[i] + 1.0f);  // +1 self-loop; deg>=1 always
    }
    if (i == 0) offs[n] = E;
}

__global__ void fill_k(const int* __restrict__ src, const int* __restrict__ dst, int* __restrict__ cursor,
                       int* __restrict__ slots, int E) {
    int i = blockIdx.x * blockDim.x + threadIdx.x;
    int stride = gridDim.x * blockDim.x;
    for (; i < E; i += stride) {
        int d = dst[i];
        int p = atomicAdd(&cursor[d], 1);
        slots[p] = src[i];
    }
}

// ---------------- GEMMs (fp32 vector; W in LDS; 4 rows per wave) ----------------

// y1[row][c] = dinv[row]*sum_k x[row][k]*W1[k][c].  Wave handles 4 rows; lane = col, col+64.
// Each ds_read of W feeds 4 FMAs -> LDS-port floor /4; x rows come in as s_load streams.
__global__ __launch_bounds__(1024) void gemm1_k(const float* __restrict__ x, const float* __restrict__ W1,
                                                const float* __restrict__ dinv, float* __restrict__ y1, int n) {
    __shared__ float Ws[NF0 * F1];  // 153.6 KB -> 1 block/CU
    {
        const float4* W4 = (const float4*)W1;
        float4* S4 = (float4*)Ws;
        for (int i = threadIdx.x; i < NF0 * F1 / 4; i += 1024) S4[i] = W4[i];
    }
    __syncthreads();
    int gtid = blockIdx.x * 1024 + threadIdx.x;
    int wid = gtid >> 6;
    int lane = threadIdx.x & 63;
    int nw = (gridDim.x * 1024) >> 6;
    int ngroups = (n + 3) >> 2;
    for (int g = wid; g < ngroups; g += nw) {
        int r0 = __builtin_amdgcn_readfirstlane(g << 2);
        if (r0 + 3 < n) {
            const float* x0 = x + (size_t)r0 * NF0;
            const float* x1 = x0 + NF0;
            const float* x2 = x1 + NF0;
            const float* x3 = x2 + NF0;
            float a00 = 0.f, a01 = 0.f, a10 = 0.f, a11 = 0.f;
            float a20 = 0.f, a21 = 0.f, a30 = 0.f, a31 = 0.f;
            for (int k = 0; k < NF0; k += 4) {
#pragma unroll
                for (int kk = 0; kk < 4; ++kk) {
                    float w0 = Ws[(k + kk) * F1 + lane];
                    float w1 = Ws[(k + kk) * F1 + 64 + lane];
                    float v0 = x0[k + kk], v1 = x1[k + kk], v2 = x2[k + kk], v3 = x3[k + kk];
                    a00 = fmaf(v0, w0, a00); a01 = fmaf(v0, w1, a01);
                    a10 = fmaf(v1, w0, a10); a11 = fmaf(v1, w1, a11);
                    a20 = fmaf(v2, w0, a20); a21 = fmaf(v2, w1, a21);
                    a30 = fmaf(v3, w0, a30); a31 = fmaf(v3, w1, a31);
                }
            }
            float d0 = dinv[r0], d1 = dinv[r0 + 1], d2 = dinv[r0 + 2], d3 = dinv[r0 + 3];
            float* yr = y1 + (size_t)r0 * F1;
            yr[lane] = a00 * d0;             yr[64 + lane] = a01 * d0;
            yr[F1 + lane] = a10 * d1;        yr[F1 + 64 + lane] = a11 * d1;
            yr[2 * F1 + lane] = a20 * d2;    yr[2 * F1 + 64 + lane] = a21 * d2;
            yr[3 * F1 + lane] = a30 * d3;    yr[3 * F1 + 64 + lane] = a31 * d3;
        } else {  // tail group (<=1 per grid-stride pass)
            for (int r = r0; r < n; ++r) {
                const float* xr = x + (size_t)r * NF0;
                float a0 = 0.f, a1 = 0.f;
                for (int k = 0; k < NF0; ++k) {
                    float xv = xr[k];
                    a0 = fmaf(xv, Ws[k * F1 + lane], a0);
                    a1 = fmaf(xv, Ws[k * F1 + 64 + lane], a1);
                }
                float dv = dinv[r];
                y1[(size_t)r * F1 + lane] = a0 * dv;
                y1[(size_t)r * F1 + 64 + lane] = a1 * dv;
            }
        }
    }
}

// y2[row][c] = dinv[row]*sum_k h[row][k]*W2[k][c].  4 rows/wave; lane = col.
__global__ __launch_bounds__(256) void gemm2_k(const float* __restrict__ h, const float* __restrict__ W2,
                                               const float* __restrict__ dinv, float* __restrict__ y2, int n) {
    __shared__ float Ws[F1 * F2];  // 32 KB
    {
        const float4* W4 = (const float4*)W2;
        float4* S4 = (float4*)Ws;
        for (int i = threadIdx.x; i < F1 * F2 / 4; i += 256) S4[i] = W4[i];
    }
    __syncthreads();
    int gtid = blockIdx.x * 256 + threadIdx.x;
    int wid = gtid >> 6;
    int lane = threadIdx.x & 63;
    int nw = (gridDim.x * 256) >> 6;
    int ngroups = (n + 3) >> 2;
    for (int g = wid; g < ngroups; g += nw) {
        int r0 = __builtin_amdgcn_readfirstlane(g << 2);
        if (r0 + 3 < n) {
            const float* h0 = h + (size_t)r0 * F1;
            const float* h1 = h0 + F1;
            const float* h2 = h1 + F1;
            const float* h3 = h2 + F1;
            float a0 = 0.f, a1 = 0.f, a2 = 0.f, a3 = 0.f;
            for (int k = 0; k < F1; k += 4) {
#pragma unroll
                for (int kk = 0; kk < 4; ++kk) {
                    float w = Ws[(k + kk) * F2 + lane];
                    a0 = fmaf(h0[k + kk], w, a0);
                    a1 = fmaf(h1[k + kk], w, a1);
                    a2 = fmaf(h2[k + kk], w, a2);
                    a3 = fmaf(h3[k + kk], w, a3);
                }
            }
            y2[(size_t)r0 * F2 + lane] = a0 * dinv[r0];
            y2[(size_t)(r0 + 1) * F2 + lane] = a1 * dinv[r0 + 1];
            y2[(size_t)(r0 + 2) * F2 + lane] = a2 * dinv[r0 + 2];
            y2[(size_t)(r0 + 3) * F2 + lane] = a3 * dinv[r0 + 3];
        } else {
            for (int r = r0; r < n; ++r) {
                const float* hr = h + (size_t)r * F1;
                float a = 0.f;
                for (int k = 0; k < F1; ++k) a = fmaf(hr[k], Ws[k * F2 + lane], a);
                y2[(size_t)r * F2 + lane] = a * dinv[r];
            }
        }
    }
}

// ---------------- Pull aggregation (CSR; wave-per-node; 8 gathers in flight) ----------------

__global__ __launch_bounds__(256) void agg1_k(const float* __restrict__ y1, const int* __restrict__ offs,
                                              const int* __restrict__ slots, const float* __restrict__ dinv,
                                              const float* __restrict__ b1, float* __restrict__ hrelu, int n) {
    int gtid = blockIdx.x * 256 + threadIdx.x;
    int wid = gtid >> 6, lane = threadIdx.x & 63;
    int nw = (gridDim.x * 256) >> 6;
    int c = lane * 2;
    for (int i = wid; i < n; i += nw) {
        int row = __builtin_amdgcn_readfirstlane(i);
        int beg = offs[row], end = offs[row + 1];
        float2 acc = *(const float2*)(y1 + (size_t)row * F1 + c);  // self-loop term
        int j = beg;
        while (j < end) {
            int m = min(64, end - j);
            int sv = (lane < m) ? slots[j + lane] : 0;
            int t = 0;
            for (; t + 8 <= m; t += 8) {  // 8 gathers in flight
                float2 v0 = *(const float2*)(y1 + (size_t)__shfl(sv, t) * F1 + c);
                float2 v1 = *(const float2*)(y1 + (size_t)__shfl(sv, t + 1) * F1 + c);
                float2 v2 = *(const float2*)(y1 + (size_t)__shfl(sv, t + 2) * F1 + c);
                float2 v3 = *(const float2*)(y1 + (size_t)__shfl(sv, t + 3) * F1 + c);
                float2 v4 = *(const float2*)(y1 + (size_t)__shfl(sv, t + 4) * F1 + c);
                float2 v5 = *(const float2*)(y1 + (size_t)__shfl(sv, t + 5) * F1 + c);
                float2 v6 = *(const float2*)(y1 + (size_t)__shfl(sv, t + 6) * F1 + c);
                float2 v7 = *(const float2*)(y1 + (size_t)__shfl(sv, t + 7) * F1 + c);
                acc.x += ((v0.x + v1.x) + (v2.x + v3.x)) + ((v4.x + v5.x) + (v6.x + v7.x));
                acc.y += ((v0.y + v1.y) + (v2.y + v3.y)) + ((v4.y + v5.y) + (v6.y + v7.y));
            }
            for (; t < m; ++t) {
                float2 v = *(const float2*)(y1 + (size_t)__shfl(sv, t) * F1 + c);
                acc.x += v.x;
                acc.y += v.y;
            }
            j += m;
        }
        float dv = dinv[row];
        float2 bb = *(const float2*)(b1 + c);
        float2 hv;
        hv.x = fmaxf(fmaf(acc.x, dv, bb.x), 0.f);
        hv.y = fmaxf(fmaf(acc.y, dv, bb.y), 0.f);
        *(float2*)(hrelu + (size_t)row * F1 + c) = hv;
    }
}

__global__ __launch_bounds__(256) void agg2_k(const float* __restrict__ y2, const int* __restrict__ offs,
                                              const int* __restrict__ slots, const float* __restrict__ dinv,
                                              const float* __restrict__ b2, float* __restrict__ out, int n) {
    int gtid = blockIdx.x * 256 + threadIdx.x;
    int wid = gtid >> 6, lane = threadIdx.x & 63;
    int nw = (gridDim.x * 256) >> 6;
    for (int i = wid; i < n; i += nw) {
        int row = __builtin_amdgcn_readfirstlane(i);
        int beg = offs[row], end = offs[row + 1];
        float acc = y2[(size_t)row * F2 + lane];  // self-loop term
        int j = beg;
        while (j < end) {
            int m = min(64, end - j);
            int sv = (lane < m) ? slots[j + lane] : 0;
            int t = 0;
            for (; t + 8 <= m; t += 8) {
                float v0 = y2[(size_t)__shfl(sv, t) * F2 + lane];
                float v1 = y2[(size_t)__shfl(sv, t + 1) * F2 + lane];
                float v2 = y2[(size_t)__shfl(sv, t + 2) * F2 + lane];
                float v3 = y2[(size_t)__shfl(sv, t + 3) * F2 + lane];
                float v4 = y2[(size_t)__shfl(sv, t + 4) * F2 + lane];
                float v5 = y2[(size_t)__shfl(sv, t + 5) * F2 + lane];
                float v6 = y2[(size_t)__shfl(sv, t + 6) * F2 + lane];
                float v7 = y2[(size_t)__shfl(sv, t + 7) * F2 + lane];
                acc += ((v0 + v1) + (v2 + v3)) + ((v4 + v5) + (v6 + v7));
            }
            for (; t < m; ++t) acc += y2[(size_t)__shfl(sv, t) * F2 + lane];
            j += m;
        }
        out[(size_t)row * F2 + lane] = fmaf(acc, dinv[row], b2[lane]);
    }
}

// ---------------- launch ----------------

extern "C" void kernel_launch(void* const* d_in, const int* in_sizes, int n_in,
                              void* d_out, int out_size, void* d_ws, size_t ws_size,
                              hipStream_t stream) {
    const float* x  = (const float*)d_in[0];
    const int*   ei = (const int*)d_in[1];
    const float* W1 = (const float*)d_in[2];
    const float* b1 = (const float*)d_in[3];
    const float* W2 = (const float*)d_in[4];
    const float* b2 = (const float*)d_in[5];
    float* out = (float*)d_out;

    int n = in_sizes[0] / NF0;
    int E = in_sizes[1] / 2;
    const int* srcv = ei;      // edge_index[0]
    const int* dstv = ei + E;  // edge_index[1]

    char* ws = (char*)d_ws;
    size_t off = 0;
    auto alloc = [&](size_t bytes) -> void* {
        void* p = ws + off;
        off = (off + bytes + 255) & ~(size_t)255;
        return p;
    };
    float* dinv   = (float*)alloc((size_t)n * 4);
    int* cnt      = (int*)alloc((size_t)n * 4);
    int* offs     = (int*)alloc((size_t)(n + 1) * 4);
    int* cursor   = (int*)alloc((size_t)n * 4);
    int* partials = (int*)alloc(((size_t)(n + 1023) / 1024) * 4);
    int* slots    = (int*)alloc((size_t)E * 4);
    float* y1     = (float*)alloc((size_t)n * F1 * 4);
    float* hrelu  = (float*)alloc((size_t)n * F1 * 4);
    float* y2     = y1;  // y1 dead after agg1; reuse

    int nchunks = (n + 1023) / 1024;

    hipMemsetAsync(cnt, 0, (size_t)n * 4, stream);
    hist_k<<<4096, 256, 0, stream>>>(dstv, cnt, E);
    scanA_k<<<nchunks, 1024, 0, stream>>>(cnt, offs, partials, n);
    scanB_k<<<1, 128, 0, stream>>>(partials, nchunks);
    scanC_k<<<(n + 255) / 256, 256, 0, stream>>>(offs, partials, cursor, cnt, dinv, n, E);
    fill_k<<<4096, 256, 0, stream>>>(srcv, dstv, cursor, slots, E);

    gemm1_k<<<256, 1024, 0, stream>>>(x, W1, dinv, y1, n);
    agg1_k<<<2048, 256, 0, stream>>>(y1, offs, slots, dinv, b1, hrelu, n);
    gemm2_k<<<1024, 256, 0, stream>>>(hrelu, W2, dinv, y2, n);
    agg2_k<<<2048, 256, 0, stream>>>(y2, offs, slots, dinv, b2, out, n);
}